// Round 11
// baseline (245.733 us; speedup 1.0000x reference)
//
#include <hip/hip_runtime.h>
#include <stdint.h>

typedef unsigned int uint;
typedef unsigned short ushort;
typedef __attribute__((ext_vector_type(8))) short short8;
typedef __attribute__((ext_vector_type(16))) float floatx16;

#define MEG (1024u * 1024u)

// ---------- helpers ----------
__device__ inline ushort f2b(float f) {           // fp32 -> bf16 RNE
  union { float f; uint u; } c; c.f = f;
  uint u = c.u;
  u = (u + 0x7fffu + ((u >> 16) & 1u)) >> 16;
  return (ushort)u;
}
__device__ inline float b2f(ushort u) {
  union { uint i; float f; } c; c.i = ((uint)u) << 16; return c.f;
}

__device__ inline void gl_lds16(const ushort* g, ushort* l) {
  // async global->LDS, 16B/lane; LDS dest = wave-uniform base + lane*16
  __builtin_amdgcn_global_load_lds(
      (const __attribute__((address_space(1))) void*)g,
      (__attribute__((address_space(3))) void*)l, 16, 0, 0);
}

// ---------------------------------------------------------------------------
// fp32->bf16 convert (x: 4096 blocks, W: 3x512 blocks).
// ---------------------------------------------------------------------------
__global__ __launch_bounds__(256) void cvt_all(
    const float* __restrict__ x,  const float* __restrict__ wq,
    const float* __restrict__ wk, const float* __restrict__ wv,
    ushort* __restrict__ xb, ushort* __restrict__ wb)
{
  const int b = blockIdx.x;
  const float* s; ushort* d; int i;
  if (b < 4096) {
    s = x; d = xb; i = b * 256 + threadIdx.x;
  } else {
    int t = b - 4096;
    int wsel = t >> 9;
    s = (wsel == 0) ? wq : (wsel == 1) ? wk : wv;
    d = wb + (size_t)wsel * MEG;
    i = (t & 511) * 256 + threadIdx.x;
  }
  float4 a = ((const float4*)s)[i * 2];
  float4 c = ((const float4*)s)[i * 2 + 1];
  short8 v;
  v[0] = (short)f2b(a.x); v[1] = (short)f2b(a.y);
  v[2] = (short)f2b(a.z); v[3] = (short)f2b(a.w);
  v[4] = (short)f2b(c.x); v[5] = (short)f2b(c.y);
  v[6] = (short)f2b(c.z); v[7] = (short)f2b(c.w);
  ((short8*)d)[i] = v;
}

// ---------------------------------------------------------------------------
// R3-proven GEMM-BT core:  C[m][n] = f( sum_k A[m][k] * B[n][k] )
// 128 x BN block tile, BK=64, 256 thr = 2x2 waves, MFMA 32x32x16
// (floatx16 acc), global_load_lds width-16 staging into XOR-swizzled
// [rows][64] LDS tiles (chunk' = chunk ^ ((r^(r>>3))&7)) — 0 bank conflicts
// measured.  2-barrier loop {sync; STAGE; sync; compute} at 4 blocks/CU.
// K-LOOP IS FROZEN: R12/R13 (single-block schedules), R16/R17 (BK=32, any
// swizzle: sub-128B-row LDS is structurally 4-way conflicted), R15 (PV
// BN=64), R18 (PV BK=128), R19 (PV dbuf), R20 (PV split-K), R6 (XCD
// swizzle) — all measured regressions. Do not retry.
//
// R21 (this round): MODE-1 epilogue rebuilt — the old one did 160 shfl_xor
// (32 x 5-level Lp reductions) + 64 SCALAR 2B global stores per thread;
// S ran ~491 TF vs QKV 718 with an identical mainloop (prior session),
// implicating ~25-30us of epilogue. New: stage p-tile in LDS (reuses the
// As|Bs 32KB exactly, swizzled with the proven >=128B-row key), row-sum by
// 128 threads linearly (kills all shfls; Lp shrinks 32->16 partials), then
// 8 passes of coalesced 16B P stores (256B/row segments).
//
// MODE 0: fused-QKV split (n<2048 -> Q/K bf16 row-major, else Vt^T)
// MODE 1: p = exp2(s*scale) bf16 out via LDS; per-block full-width row sums
//         plain-stored to Lp[nb][bz][2048] (no atomics; |s|*scale bounded
//         ~8 so no max subtraction needed, fp32-safe)
// MODE 2: fp32 out * 1/rowsum; rowsum = sum of 16 Lp partials
//         (cooperative prologue into LDS Linv[128])
// ---------------------------------------------------------------------------
template <int MODE, int BN>
__device__ __forceinline__ void gemm_core(
    const ushort* __restrict__ A, int lda, size_t sA,
    const ushort* __restrict__ B, int ldb, size_t sB,
    void* __restrict__ C, int ldc, size_t sC,
    int K, float scale, float* __restrict__ Lsum)
{
  constexpr int NJ = BN / 64;          // n-frags per wave (2)
  constexpr int NB = BN / 32;          // 32-row staging groups for B (4)
  // single allocation so MODE 1 can reuse As|Bs as the 128x128 p-tile
  __shared__ __align__(16) ushort smem[128 * 64 + BN * 64];
  __shared__ float Linv[(MODE == 2) ? 128 : 1];
  ushort* const As = smem;
  ushort* const Bs = smem + 128 * 64;

  const int tid = threadIdx.x;
  const int bz  = blockIdx.z;
  A += (size_t)bz * sA;
  B += (size_t)bz * sB;

  const int m0 = blockIdx.y * 128;
  const int n0 = blockIdx.x * BN;

  const int lane = tid & 63;
  const int w    = tid >> 6;
  const int l32  = lane & 31;
  const int lh   = lane >> 5;          // 0/1 -> k-half of the 16-k step
  const int mw   = w >> 1;
  const int nw   = w & 1;

  // ---- PV prologue: reduce 16 Lp partials per row -> Linv ----
  if constexpr (MODE == 2) {
    if (tid < 128) {
      float s = 0.f;
#pragma unroll
      for (int p = 0; p < 16; ++p)
        s += Lsum[((size_t)p * gridDim.z + bz) * 2048 + m0 + tid];
      Linv[tid] = 1.0f / s;
    }
    // first __syncthreads of the K-loop publishes Linv before any use
  }

  // ---- staging pointers (32 rows per group; 8 lanes per 128B row) ----
  const int srow = tid >> 3;
  const ushort* agp[4];
  const ushort* bgp[NB];
#pragma unroll
  for (int c4 = 0; c4 < 4; ++c4) {
    int r   = c4 * 32 + srow;
    int col = (((tid & 7) ^ ((r ^ (r >> 3)) & 7))) * 8;
    agp[c4] = A + (size_t)(m0 + r) * lda + col;
  }
#pragma unroll
  for (int cb = 0; cb < NB; ++cb) {
    int r   = cb * 32 + srow;
    int col = (((tid & 7) ^ ((r ^ (r >> 3)) & 7))) * 8;
    bgp[cb] = B + (size_t)(n0 + r) * ldb + col;
  }

  // ---- fragment rows + swizzle keys (loop-invariant) ----
  int arow[2], aswz[2], brow[NJ], bswz[NJ];
#pragma unroll
  for (int t = 0; t < 2; ++t) {
    arow[t] = mw * 64 + t * 32 + l32;
    aswz[t] = (arow[t] ^ (arow[t] >> 3)) & 7;
  }
#pragma unroll
  for (int t = 0; t < NJ; ++t) {
    brow[t] = nw * (BN / 2) + t * 32 + l32;
    bswz[t] = (brow[t] ^ (brow[t] >> 3)) & 7;
  }

  floatx16 acc[2][NJ];
#pragma unroll
  for (int i = 0; i < 2; ++i)
#pragma unroll
    for (int j = 0; j < NJ; ++j)
#pragma unroll
      for (int r = 0; r < 16; ++r) acc[i][j][r] = 0.f;

  for (int k0 = 0; k0 < K; k0 += 64) {
    __syncthreads();
#pragma unroll
    for (int c4 = 0; c4 < 4; ++c4) {
      gl_lds16(agp[c4], &As[(c4 * 32 + w * 8) * 64]);
      agp[c4] += 64;
    }
#pragma unroll
    for (int cb = 0; cb < NB; ++cb) {
      gl_lds16(bgp[cb], &Bs[(cb * 32 + w * 8) * 64]);
      bgp[cb] += 64;
    }
    __syncthreads();

#pragma unroll
    for (int s = 0; s < 4; ++s) {        // 4 k-steps of 16
      short8 af[2], bf[NJ];
#pragma unroll
      for (int t = 0; t < 2; ++t)
        af[t] = *(const short8*)&As[arow[t] * 64 + (((s * 2 + lh) ^ aswz[t]) * 8)];
#pragma unroll
      for (int t = 0; t < NJ; ++t)
        bf[t] = *(const short8*)&Bs[brow[t] * 64 + (((s * 2 + lh) ^ bswz[t]) * 8)];
#pragma unroll
      for (int i = 0; i < 2; ++i)
#pragma unroll
        for (int j = 0; j < NJ; ++j)
          acc[i][j] = __builtin_amdgcn_mfma_f32_32x32x16_bf16(
              af[i], bf[j], acc[i][j], 0, 0, 0);
    }
  }

  // ---- epilogue; C/D (32x32): col = lane&31, row = (reg&3)+8*(reg>>2)+4*lh
  if constexpr (MODE == 0) {   // fused-QKV split
#pragma unroll
    for (int i = 0; i < 2; ++i)
#pragma unroll
      for (int j = 0; j < NJ; ++j) {
        const int mbase = m0 + mw * 64 + i * 32 + 4 * lh;
        const int ng    = n0 + nw * (BN / 2) + j * 32 + l32;
        if (ng < 2048) {
          // Qb @ C, Kb @ C + 8M elems
          ushort* dst = (ushort*)C + (size_t)(ng >> 10) * (8u * MEG);
          const int nn = ng & 1023;
#pragma unroll
          for (int g = 0; g < 4; ++g)
#pragma unroll
            for (int r = 0; r < 4; ++r)
              dst[(size_t)(mbase + 8 * g + r) * 1024 + nn] =
                  f2b(acc[i][j][4 * g + r]);
        } else {
          // Vt @ C + 16M elems, transposed [1024][8192]
          ushort* Vo = (ushort*)C + (size_t)16 * MEG;
#pragma unroll
          for (int g = 0; g < 4; ++g) {
            uint lo = (uint)f2b(acc[i][j][4 * g + 0]) |
                      ((uint)f2b(acc[i][j][4 * g + 1]) << 16);
            uint hi = (uint)f2b(acc[i][j][4 * g + 2]) |
                      ((uint)f2b(acc[i][j][4 * g + 3]) << 16);
            *(uint2*)&Vo[(size_t)(ng - 2048) * 8192 + mbase + 8 * g] =
                make_uint2(lo, hi);
          }
        }
      }
  } else if constexpr (MODE == 1) {   // R21 LDS-staged p epilogue
    __syncthreads();                  // all waves done reading As/Bs
    ushort* const Ps = smem;          // [128][128], 16B-chunk swizzled:
                                      // phys = (c&8) | ((c&7)^key(row))
    // 1) p = exp2(s*scale) -> LDS (rows mw*64.., cols nw*64..; all covered)
#pragma unroll
    for (int i = 0; i < 2; ++i) {
      const int rb = mw * 64 + i * 32 + 4 * lh;
#pragma unroll
      for (int g = 0; g < 4; ++g)
#pragma unroll
        for (int r = 0; r < 4; ++r) {
          const int row = rb + 8 * g + r;
          const int key = (row ^ (row >> 3)) & 7;
#pragma unroll
          for (int j = 0; j < NJ; ++j) {
            const int col = nw * 64 + j * 32 + l32;
            const int c   = col >> 3;
            const int ph  = (c & 8) | ((c & 7) ^ key);
            Ps[row * 128 + ph * 8 + (col & 7)] =
                f2b(exp2f(acc[i][j][4 * g + r] * scale));
          }
        }
    }
    __syncthreads();
    // 2) per-row sums of ROUNDED p (matches what PV consumes) -> Lp,
    //    one coalesced 128-float store; kills the old 160-shfl reduction.
    float* Lp = Lsum + ((size_t)blockIdx.x * gridDim.z + bz) * 2048;
    if (tid < 128) {
      float s = 0.f;
#pragma unroll
      for (int m = 0; m < 16; ++m) {     // staggered start spreads banks
        short8 v = *(const short8*)&Ps[tid * 128 + (((m + tid) & 15) * 8)];
#pragma unroll
        for (int e = 0; e < 8; ++e) s += b2f((ushort)v[e]);
      }
      Lp[m0 + tid] = s;
    }
    // 3) coalesced P stores: 8 passes x 16B/thread (256B/row segments),
    //    un-swizzling on the LDS read side.
    ushort* Cb = (ushort*)C + (size_t)bz * sC;
#pragma unroll
    for (int q = 0; q < 8; ++q) {
      const int lin = q * 256 + tid;
      const int row = lin >> 4;
      const int c   = lin & 15;
      const int key = (row ^ (row >> 3)) & 7;
      const int ph  = (c & 8) | ((c & 7) ^ key);
      short8 v = *(const short8*)&Ps[row * 128 + ph * 8];
      *(short8*)&Cb[(size_t)(m0 + row) * ldc + n0 + c * 8] = v;
    }
  } else {                    // MODE 2: normalized fp32 output
    float* Cb = (float*)C + (size_t)bz * sC;
#pragma unroll
    for (int i = 0; i < 2; ++i) {
      const int mbase = m0 + mw * 64 + i * 32 + 4 * lh;
#pragma unroll
      for (int g = 0; g < 4; ++g)
#pragma unroll
        for (int r = 0; r < 4; ++r) {
          const int mg = mbase + 8 * g + r;
          const float inv = Linv[mg - m0];
#pragma unroll
          for (int j = 0; j < NJ; ++j) {
            const int ng = n0 + nw * (BN / 2) + j * 32 + l32;
            Cb[(size_t)mg * ldc + ng] = acc[i][j][4 * g + r] * inv;
          }
        }
    }
  }
}

// ---- distinct symbols per stage (counter attribution) ----
// (256,4): 64 VGPR + 64 AGPR = 128 unified = the 16-wave/CU boundary (m69);
// LDS 32KB/block -> 4 blocks/CU.
__global__ __launch_bounds__(256, 4) void gemm_qkv(
    const ushort* __restrict__ A, int lda, size_t sA,
    const ushort* __restrict__ B, int ldb, size_t sB,
    void* __restrict__ C, int ldc, size_t sC, int K, float scale,
    float* __restrict__ Lsum) {
  gemm_core<0, 128>(A, lda, sA, B, ldb, sB, C, ldc, sC, K, scale, Lsum);
}
// S grid is exactly 1024 blocks = 4/CU x 256 CU -> one resident round.
__global__ __launch_bounds__(256, 4) void gemm_s(
    const ushort* __restrict__ A, int lda, size_t sA,
    const ushort* __restrict__ B, int ldb, size_t sB,
    void* __restrict__ C, int ldc, size_t sC, int K, float scale,
    float* __restrict__ Lsum) {
  gemm_core<1, 128>(A, lda, sA, B, ldb, sB, C, ldc, sC, K, scale, Lsum);
}
__global__ __launch_bounds__(256, 4) void gemm_pv(
    const ushort* __restrict__ A, int lda, size_t sA,
    const ushort* __restrict__ B, int ldb, size_t sB,
    void* __restrict__ C, int ldc, size_t sC, int K, float scale,
    float* __restrict__ Lsum) {
  gemm_core<2, 128>(A, lda, sA, B, ldb, sB, C, ldc, sC, K, scale, Lsum);
}

// ---------------------------------------------------------------------------
// ws layout (ushort elems), total 80.5 MiB  (proven ws >= 90.2 MB):
//   Qb @ 0      [8192][1024]   (16 MiB)
//   Kb @ 8M     [8192][1024]   (16 MiB)
//   Vt @ 16M    [1024][8192]   (16 MiB)
//   xb @ 24M    [8192][1024]   (16 MiB)  -- dead after QKV
//   Wb @ 32M    [3072][1024]   ( 6 MiB)  -- dead after QKV
//   P  @ 24M    [4][2048][2048] (32 MiB) -- OVERLAYS xb+Wb (both dead)
//   Lp @ 40M    fp32 [16][4][2048] (512 KiB) -- per-nb full-width row sums
// ---------------------------------------------------------------------------
extern "C" void kernel_launch(void* const* d_in, const int* in_sizes, int n_in,
                              void* d_out, int out_size, void* d_ws, size_t ws_size,
                              hipStream_t stream) {
  const float* x  = (const float*)d_in[0];
  const float* Wq = (const float*)d_in[1];
  const float* Wk = (const float*)d_in[2];
  const float* Wv = (const float*)d_in[3];
  float* outp = (float*)d_out;

  const float SCALE = 1.4426950408889634f / 32.0f;   // log2(e)/sqrt(1024)

  ushort* W0 = (ushort*)d_ws;
  ushort* Qb = W0;
  ushort* Kb = W0 + (size_t)8 * MEG;
  ushort* Vt = W0 + (size_t)16 * MEG;
  ushort* xb = W0 + (size_t)24 * MEG;
  ushort* Wb = W0 + (size_t)32 * MEG;
  ushort* Pb = W0 + (size_t)24 * MEG;            // overlays xb/Wb after QKV

  // full: P[4] (32 MiB) + Lp 16*4*2048*4B (512 KiB)
  const size_t NEED_FULL = ((size_t)40 * MEG) * 2 + (size_t)16 * 4 * 2048 * 4;
  const bool full = ws_size >= NEED_FULL;
  float* Lp = full ? (float*)(W0 + (size_t)40 * MEG)
                   : (float*)(W0 + (size_t)28 * MEG);  // per-batch: P is 8 MiB

  cvt_all<<<5632, 256, 0, stream>>>(x, Wq, Wk, Wv, xb, Wb);

  // fused QKV projection: [8192x1024] x [3072x1024]^T, split epilogue
  gemm_qkv<<<dim3(24, 64, 1), 256, 0, stream>>>(
      xb, 1024, 0, Wb, 1024, 0, Qb, 1024, 0, 1024, 1.f, nullptr);

  if (full) {
    gemm_s<<<dim3(16, 16, 4), 256, 0, stream>>>(
        Qb, 1024, (size_t)2048 * 1024, Kb, 1024, (size_t)2048 * 1024,
        Pb, 2048, (size_t)2048 * 2048, 1024, SCALE, Lp);
    gemm_pv<<<dim3(8, 16, 4), 256, 0, stream>>>(
        Pb, 2048, (size_t)2048 * 2048, Vt, 8192, 2048,
        outp, 1024, (size_t)2048 * 1024, 2048, 1.f, Lp);
  } else {
    // per-batch fallback (P single batch @24M, Lp @28M; no memset needed —
    // every Lp slot is plain-stored exactly once per S launch)
    for (int b = 0; b < 4; ++b) {
      gemm_s<<<dim3(16, 16, 1), 256, 0, stream>>>(
          Qb + (size_t)b * 2048 * 1024, 1024, 0,
          Kb + (size_t)b * 2048 * 1024, 1024, 0,
          Pb, 2048, 0, 1024, SCALE, Lp);
      gemm_pv<<<dim3(8, 16, 1), 256, 0, stream>>>(
          Pb, 2048, 0, Vt + (size_t)b * 2048, 8192, 0,
          outp + (size_t)b * 2048 * 1024, 1024, 0, 2048, 1.f, Lp);
    }
  }
}